// Round 6
// baseline (7948.853 us; speedup 1.0000x reference)
//
#include <hip/hip_runtime.h>

typedef _Float16 f16x2 __attribute__((ext_vector_type(2)));
typedef _Float16 f16x4 __attribute__((ext_vector_type(4)));

union FP16U { _Float16 h; unsigned short u; };

#if __has_builtin(__builtin_amdgcn_sdot4)
__device__ __forceinline__ int sdot4(int a, int b, int c) {
    return __builtin_amdgcn_sdot4(a, b, c, false);
}
#else
__device__ __forceinline__ int sdot4(int a, int b, int c) {
#pragma unroll
    for (int i = 0; i < 4; ++i)
        c += (int)((char)(a >> (8 * i))) * (int)((char)(b >> (8 * i)));
    return c;
}
#endif

__device__ __forceinline__ float dot2acc(f16x2 a, f16x2 b, float c) {
#if __has_builtin(__builtin_amdgcn_fdot2)
    return __builtin_amdgcn_fdot2(a, b, c, false);
#else
    return c + (float)a[0] * (float)b[0] + (float)a[1] * (float)b[1];
#endif
}

__device__ __forceinline__ float sigmoidf_(float x) {
    return __builtin_amdgcn_rcpf(1.f + __expf(-x));
}

__device__ __forceinline__ float tanhf_(float x) {
    float a = fabsf(x);
    float e = __expf(-2.f * a);
    float r = (1.f - e) * __builtin_amdgcn_rcpf(1.f + e);
    return copysignf(r, x);
}

// ---------------------------------------------------------------------------
// ws layout (bytes):
//   0        whh_i8   442368   ((half*384+j)*3+g)*192+kk  (int8, per-row scale)
//   442368   wx_f16   50688    rows 1152 x 22 fp16 (padded; k<20 valid)
//   493056   w2_f16   38400    rows 48 x 400 fp16 (padded; k<384 valid)
//   531456   ch       4608     1152 f32: Whh row coef = max/16129
//   536064   c2       192      48 f32 (unused; kept for layout clarity)
//   1048576  sxT      64*2048*48 u32 tagged fp16 (tag t+1 in high16), 25.2 MB
// ---------------------------------------------------------------------------
__global__ void pack_weights(const float* __restrict__ Whh1,
                             const float* __restrict__ Wih1,
                             const float* __restrict__ Wih2,
                             char* __restrict__ wsb) {
    int r = blockIdx.x * 256 + threadIdx.x;
    char* whh = wsb;
    _Float16* wxh = (_Float16*)(wsb + 442368);
    _Float16* w2h = (_Float16*)(wsb + 493056);
    float* ch = (float*)(wsb + 531456);
    if (r < 1152) {
        int g = r / 384, j = r % 384;
        float mx = 0.f;
        for (int k = 0; k < 384; ++k) mx = fmaxf(mx, fabsf(Whh1[r * 384 + k]));
        float inv = (mx > 0.f) ? 127.f / mx : 0.f;
        ch[r] = mx / 16129.f;
        for (int half = 0; half < 2; ++half)
            for (int kk = 0; kk < 192; ++kk) {
                int q = (int)rintf(Whh1[r * 384 + half * 192 + kk] * inv);
                whh[((half * 384 + j) * 3 + g) * 192 + kk] = (char)q;
            }
    } else if (r < 2304) {
        int rr = r - 1152;
        for (int k = 0; k < 20; ++k) wxh[rr * 22 + k] = (_Float16)Wih1[rr * 20 + k];
        wxh[rr * 22 + 20] = (_Float16)0.f;
        wxh[rr * 22 + 21] = (_Float16)0.f;
    } else if (r < 2352) {
        int o = r - 2304;
        for (int k = 0; k < 384; ++k) w2h[o * 400 + k] = (_Float16)Wih2[o * 384 + k];
        for (int k = 384; k < 400; ++k) w2h[o * 400 + k] = (_Float16)0.f;
    }
}

// ---------------------------------------------------------------------------
// gru_main: blocks 0..63 = GRU1 producers (one CU per batch; int8 gate
// weights in VGPRs; n-gate h-residual; fp16 x-proj + fp16 GRU2-proj).
// Blocks 64..127 = GRU2+ReLU+FC consumers (overlapped via tagged words).
// ---------------------------------------------------------------------------
__global__ __launch_bounds__(768, 3) void gru_main(
    const float* __restrict__ x, const float* __restrict__ h1_0,
    const float* __restrict__ h2_0,
    const float* __restrict__ bih1, const float* __restrict__ bhh1,
    const char* __restrict__ wsb,
    const float* __restrict__ Whh2, const float* __restrict__ bih2,
    const float* __restrict__ bhh2,
    const float* __restrict__ Wfc, const float* __restrict__ bfc,
    unsigned* __restrict__ sxT, float* __restrict__ xmid,
    float* __restrict__ h1f_o, float* __restrict__ h2f_o) {
    const int bid = blockIdx.x;
    const int tid = threadIdx.x;

    if (bid >= 64) {
        // ------------- consumer: GRU2 + ReLU + FC + 2*tanh -------------
        if (tid >= 64) return;
        const int b = bid - 64, l = tid;
        float w2r[16]; float bx2 = 0.f, bh2 = 0.f;
        if (l < 48) {
#pragma unroll
            for (int k = 0; k < 16; ++k) w2r[k] = Whh2[l * 16 + k];
            bx2 = bih2[l]; bh2 = bhh2[l];
        }
        float wfc[16]; float bf = 0.f;
        if (l < 20) {
#pragma unroll
            for (int k = 0; k < 16; ++k) wfc[k] = Wfc[l * 16 + k];
            bf = bfc[l];
        }
        float h2 = (l < 16) ? h2_0[b * 16 + l] : 0.f;
        float* xm = xmid + (size_t)b * 40960;
        const unsigned* sxb = sxT + (size_t)b * 2048 * 48;
        unsigned cur = 0;
        if (l < 48) {
            do {
                cur = __hip_atomic_load(&sxb[l], __ATOMIC_RELAXED,
                                        __HIP_MEMORY_SCOPE_AGENT);
            } while ((cur >> 16) != 1u);
        }
        for (int t = 0; t < 2048; ++t) {
            unsigned nxt = 0;
            if (l < 48 && t + 1 < 2048)
                nxt = __hip_atomic_load(&sxb[(size_t)(t + 1) * 48 + l],
                                        __ATOMIC_RELAXED, __HIP_MEMORY_SCOPE_AGENT);
            FP16U vv; vv.u = (unsigned short)(cur & 0xffffu);
            float ax = (float)vv.h + bx2;
            float ah = bh2;
#pragma unroll
            for (int k = 0; k < 16; ++k) ah += __shfl(h2, k) * w2r[k];
            float s_   = ax + ah;
            float zpre = __shfl(s_, (16 + l) & 63);
            float xn3  = __shfl(ax, (32 + l) & 63);
            float ghn  = __shfl(ah, (32 + l) & 63);
            float r2 = sigmoidf_(s_);
            float z2 = sigmoidf_(zpre);
            float n2 = tanhf_(xn3 + r2 * ghn);
            float h2n = (1.f - z2) * n2 + z2 * h2;
            if (l < 16) h2 = h2n;
            float y2 = fmaxf(h2n, 0.f);
            float a = bf;
#pragma unroll
            for (int k = 0; k < 16; ++k) a += __shfl(y2, k) * wfc[k];
            if (l < 20) xm[t * 20 + l] = 2.f * tanhf_(a);
            if (l < 48 && t + 1 < 2048) {
                unsigned want = (unsigned)(t + 2);
                while ((nxt >> 16) != want) {
                    __builtin_amdgcn_s_sleep(1);
                    nxt = __hip_atomic_load(&sxb[(size_t)(t + 1) * 48 + l],
                                            __ATOMIC_RELAXED,
                                            __HIP_MEMORY_SCOPE_AGENT);
                }
                cur = nxt;
            }
        }
        if (l < 16) h2f_o[b * 16 + l] = h2;
        return;
    }

    // ----------------------------- producer -----------------------------
    const int b = bid;
    const int half = tid / 384, jl = tid % 384;

    __shared__ __align__(16) char h1i[512];
    __shared__ __align__(16) char h1r[512];
    __shared__ __align__(16) _Float16 h1h[384];
    __shared__ __align__(16) _Float16 w2L[48 * 400];
    __shared__ __align__(16) _Float16 wxL[1152 * 22];
    __shared__ __align__(16) _Float16 xsh[24];
    __shared__ float xpL[2][1152];
    __shared__ int ph[8 * 384];
    __shared__ float p2[48 * 17];
    __shared__ float chL[1152], cbA[1536];

    // gate weights into registers (int8 packed dwords; r,z,n)
    int4 Wr[12], Wz[12], Wn[12];
    {
        const int4* wp = (const int4*)wsb;
        const int base = (half * 384 + jl) * 36;
#pragma unroll
        for (int m = 0; m < 12; ++m) {
            Wr[m] = wp[base + m];
            Wz[m] = wp[base + 12 + m];
            Wn[m] = wp[base + 24 + m];
        }
    }
    // cooperative LDS fills
    for (int i = tid; i < 9600; i += 768)
        ((int*)w2L)[i] = ((const int*)(wsb + 493056))[i];
    for (int i = tid; i < 12672; i += 768)
        ((int*)wxL)[i] = ((const int*)(wsb + 442368))[i];
    for (int i = tid; i < 1152; i += 768)
        chL[i] = ((const float*)(wsb + 531456))[i];
    for (int i = tid; i < 384; i += 768) {
        cbA[i]        = bih1[i] + bhh1[i];
        cbA[384 + i]  = bih1[384 + i] + bhh1[384 + i];
        cbA[768 + i]  = bih1[768 + i];
        cbA[1152 + i] = bhh1[768 + i];
    }
    float hprev = 0.f;
    if (tid < 384) {
        hprev = h1_0[b * 384 + tid];
        float hs = fminf(fmaxf(hprev * 127.f, -127.f), 127.f);
        int q1 = (int)rintf(hs);
        int q2 = (int)rintf((hs - (float)q1) * 256.f);
        q2 = min(127, max(-127, q2));
        h1i[tid] = (char)q1;
        h1r[tid] = (char)q2;
        h1h[tid] = (_Float16)hprev;
    }
    const float* xb = x + (size_t)b * 40960;
    if (tid >= 704 && tid < 709) {
        int i = tid - 704;
        float4 v = *(const float4*)(xb + i * 4);
        f16x4 hv = {(_Float16)v.x, (_Float16)v.y, (_Float16)v.z, (_Float16)v.w};
        ((f16x4*)xsh)[i] = hv;
    }
    const int o2 = tid >> 4, seg = tid & 15;
    const f16x2* w2row = (const f16x2*)(w2L + o2 * 400 + seg * 24);
    unsigned* sxb = sxT + (size_t)b * 2048 * 48;

    __syncthreads();
    // prologue: xpL[0] for step 0
    if (tid >= 384) {
        const int u = tid - 384;
        const f16x2* xv2 = (const f16x2*)xsh;
#pragma unroll
        for (int rr = 0; rr < 3; ++rr) {
            const int r = 3 * u + rr;
            const f16x2* wp2 = (const f16x2*)(wxL + r * 22);
            float acc = 0.f;
#pragma unroll
            for (int k = 0; k < 10; ++k) acc = dot2acc(wp2[k], xv2[k], acc);
            xpL[0][r] = acc;
        }
    }
    __syncthreads();

    for (int t = 0; t < 2048; ++t) {
        // ---------------- phase A ----------------
        if (tid >= 704 && tid < 709 && t + 1 < 2048) {
            int i = tid - 704;
            float4 v = *(const float4*)(xb + (size_t)(t + 1) * 20 + i * 4);
            f16x4 hv = {(_Float16)v.x, (_Float16)v.y, (_Float16)v.z, (_Float16)v.w};
            ((f16x4*)xsh)[i] = hv;
        }
        // gate dots: r,z,n from q1; n-residual from q2 (reuses Wn)
        int ir = 0, iz = 0, in1 = 0, in2 = 0;
        {
            const int4* hq1 = (const int4*)(h1i + half * 192);
            const int4* hq2 = (const int4*)(h1r + half * 192);
#pragma unroll
            for (int m = 0; m < 12; ++m) {
                int4 a = hq1[m];
                ir = sdot4(Wr[m].x, a.x, ir); ir = sdot4(Wr[m].y, a.y, ir);
                ir = sdot4(Wr[m].z, a.z, ir); ir = sdot4(Wr[m].w, a.w, ir);
                iz = sdot4(Wz[m].x, a.x, iz); iz = sdot4(Wz[m].y, a.y, iz);
                iz = sdot4(Wz[m].z, a.z, iz); iz = sdot4(Wz[m].w, a.w, iz);
                in1 = sdot4(Wn[m].x, a.x, in1); in1 = sdot4(Wn[m].y, a.y, in1);
                in1 = sdot4(Wn[m].z, a.z, in1); in1 = sdot4(Wn[m].w, a.w, in1);
                int4 c = hq2[m];
                in2 = sdot4(Wn[m].x, c.x, in2); in2 = sdot4(Wn[m].y, c.y, in2);
                in2 = sdot4(Wn[m].z, c.z, in2); in2 = sdot4(Wn[m].w, c.w, in2);
            }
        }
        ph[half * 384 + jl]        = ir;
        ph[768 + half * 384 + jl]  = iz;
        ph[1536 + half * 384 + jl] = in1;
        ph[2304 + half * 384 + jl] = in2;
        // xp2 partials (fp16): output step t-1 (h1h = y1[t-1])
        if (t > 0) {
            const f16x2* hp = (const f16x2*)(h1h + seg * 24);
            float a = 0.f;
#pragma unroll
            for (int m = 0; m < 12; ++m) a = dot2acc(w2row[m], hp[m], a);
            p2[o2 * 17 + seg] = a;
        }
        __syncthreads();  // S1

        // ---------------- phase B ----------------
        if (tid < 384) {
            const int j = tid;
            float sr = (float)(ph[j] + ph[384 + j]);
            float sz = (float)(ph[768 + j] + ph[1152 + j]);
            float sn1 = (float)(ph[1536 + j] + ph[1920 + j]);
            float sn2 = (float)(ph[2304 + j] + ph[2688 + j]);
            const float* xp = xpL[t & 1];
            float ar = sr * chL[j] + xp[j] + cbA[j];
            float az = sz * chL[384 + j] + xp[384 + j] + cbA[384 + j];
            float xn = xp[768 + j] + cbA[768 + j];
            float hn_ = (sn1 + sn2 * 0.00390625f) * chL[768 + j] + cbA[1152 + j];
            float r = sigmoidf_(ar), z = sigmoidf_(az);
            float n = tanhf_(xn + r * hn_);
            hprev = (1.f - z) * n + z * hprev;
            float hs = fminf(fmaxf(hprev * 127.f, -127.f), 127.f);
            int q1 = (int)rintf(hs);
            int q2 = (int)rintf((hs - (float)q1) * 256.f);
            q2 = min(127, max(-127, q2));
            h1i[j] = (char)q1;
            h1r[j] = (char)q2;
            h1h[j] = (_Float16)hprev;
            if (t > 0 && j < 48) {
                const float* pr = p2 + j * 17;
                float s0 = 0.f, s1 = 0.f;
#pragma unroll
                for (int k = 0; k < 8; ++k) { s0 += pr[k]; s1 += pr[8 + k]; }
                FP16U v; v.h = (_Float16)(s0 + s1);
                __hip_atomic_store(&sxb[(size_t)(t - 1) * 48 + j],
                                   ((unsigned)t << 16) | (unsigned)v.u,
                                   __ATOMIC_RELAXED, __HIP_MEMORY_SCOPE_AGENT);
            }
        } else if (t + 1 < 2048) {
            // x-projection for step t+1
            const int u = tid - 384;
            float* xpn = xpL[(t + 1) & 1];
            const f16x2* xv2 = (const f16x2*)xsh;
#pragma unroll
            for (int rr = 0; rr < 3; ++rr) {
                const int r = 3 * u + rr;
                const f16x2* wp2 = (const f16x2*)(wxL + r * 22);
                float acc = 0.f;
#pragma unroll
                for (int k = 0; k < 10; ++k) acc = dot2acc(wp2[k], xv2[k], acc);
                xpn[r] = acc;
            }
        }
        __syncthreads();  // S2
    }
    // epilogue: publish xp2 for step 2047 (h1h = y1[2047])
    {
        const f16x2* hp = (const f16x2*)(h1h + seg * 24);
        float a = 0.f;
#pragma unroll
        for (int m = 0; m < 12; ++m) a = dot2acc(w2row[m], hp[m], a);
        p2[o2 * 17 + seg] = a;
    }
    __syncthreads();
    if (tid < 48) {
        const float* pr = p2 + tid * 17;
        float s0 = 0.f, s1 = 0.f;
#pragma unroll
        for (int k = 0; k < 8; ++k) { s0 += pr[k]; s1 += pr[8 + k]; }
        FP16U v; v.h = (_Float16)(s0 + s1);
        __hip_atomic_store(&sxb[(size_t)2047 * 48 + tid],
                           (2048u << 16) | (unsigned)v.u,
                           __ATOMIC_RELAXED, __HIP_MEMORY_SCOPE_AGENT);
    }
    if (tid < 384) h1f_o[b * 384 + tid] = hprev;
}

// ---------------------------------------------------------------------------
// GRU3 on flip(x_mid): wave0 computes x-projection into an LDS ring (4-deep
// global prefetch); wave1 runs the recurrent chain. One block per batch.
// ---------------------------------------------------------------------------
__global__ __launch_bounds__(128) void gru3_bwd(
    const float* __restrict__ xmid, const float* __restrict__ h3_0,
    const float* __restrict__ Wih3, const float* __restrict__ Whh3,
    const float* __restrict__ bih3, const float* __restrict__ bhh3,
    float* __restrict__ xout, float* __restrict__ h3f_o) {
    const int b = blockIdx.x, tid = threadIdx.x;
    __shared__ float ring[128 * 64];
    __shared__ int flags[128];
    __shared__ int consL;
    if (tid < 128) flags[tid] = 0;
    if (tid == 0) consL = 0;
    __syncthreads();
    const float* xm = xmid + (size_t)b * 40960;

    if (tid < 64) {
        const int l = tid;
        float wi3[20]; float bx3 = 0.f;
        if (l < 60) {
#pragma unroll
            for (int k = 0; k < 20; ++k) wi3[k] = Wih3[l * 20 + k];
            bx3 = bih3[l];
        }
        float pr[4];
#pragma unroll
        for (int i = 0; i < 4; ++i)
            pr[i] = (l < 20) ? xm[(2047 - i) * 20 + l] : 0.f;
        int lastcons = 0;
        for (int s = 0; s < 2048; ++s) {
            if (s - lastcons >= 112) {
                do {
                    lastcons = __hip_atomic_load(&consL, __ATOMIC_RELAXED,
                                                 __HIP_MEMORY_SCOPE_WORKGROUP);
                } while (s - lastcons >= 112);
            }
            float xv = pr[s & 3];
            if (l < 20 && s + 4 < 2048) pr[s & 3] = xm[(2043 - s) * 20 + l];
            float ax = bx3;
#pragma unroll
            for (int k = 0; k < 20; ++k) ax += __shfl(xv, k) * wi3[k];
            if (l < 60) ring[(s & 127) * 64 + l] = ax;
            __threadfence_block();
            if (l == 0)
                __hip_atomic_store(&flags[s & 127], s + 1, __ATOMIC_RELEASE,
                                   __HIP_MEMORY_SCOPE_WORKGROUP);
        }
    } else {
        const int l = tid - 64;
        float wh3[20]; float bh3v = 0.f;
        if (l < 60) {
#pragma unroll
            for (int k = 0; k < 20; ++k) wh3[k] = Whh3[l * 20 + k];
            bh3v = bhh3[l];
        }
        float h3 = (l < 20) ? h3_0[b * 20 + l] : 0.f;
        float* xo = xout + (size_t)b * 40960;
        for (int s = 0; s < 2048; ++s) {
            while (__hip_atomic_load(&flags[s & 127], __ATOMIC_ACQUIRE,
                                     __HIP_MEMORY_SCOPE_WORKGROUP) != s + 1) {}
            float ax = (l < 60) ? ring[(s & 127) * 64 + l] : 0.f;
            float ah = bh3v;
#pragma unroll
            for (int k = 0; k < 20; ++k) ah += __shfl(h3, k) * wh3[k];
            float s_   = ax + ah;
            float zpre = __shfl(s_, (20 + l) & 63);
            float xn_  = __shfl(ax, (40 + l) & 63);
            float ghn  = __shfl(ah, (40 + l) & 63);
            float r = sigmoidf_(s_);
            float z = sigmoidf_(zpre);
            float n = tanhf_(xn_ + r * ghn);
            float hn = (1.f - z) * n + z * h3;
            if (l < 20) {
                h3 = hn;
                xo[s * 20 + l] = tanhf_(hn);
            }
            if (l == 0 && (s & 31) == 31)
                __hip_atomic_store(&consL, s + 1, __ATOMIC_RELAXED,
                                   __HIP_MEMORY_SCOPE_WORKGROUP);
        }
        if (l < 20) h3f_o[b * 20 + l] = h3;
    }
}

extern "C" void kernel_launch(void* const* d_in, const int* in_sizes, int n_in,
                              void* d_out, int out_size, void* d_ws, size_t ws_size,
                              hipStream_t stream) {
    const float* x    = (const float*)d_in[0];
    const float* h1   = (const float*)d_in[1];
    const float* h2   = (const float*)d_in[2];
    const float* h3   = (const float*)d_in[3];
    const float* Wih1 = (const float*)d_in[4];
    const float* Whh1 = (const float*)d_in[5];
    const float* bih1 = (const float*)d_in[6];
    const float* bhh1 = (const float*)d_in[7];
    const float* Wih2 = (const float*)d_in[8];
    const float* Whh2 = (const float*)d_in[9];
    const float* bih2 = (const float*)d_in[10];
    const float* bhh2 = (const float*)d_in[11];
    const float* Wih3 = (const float*)d_in[12];
    const float* Whh3 = (const float*)d_in[13];
    const float* bih3 = (const float*)d_in[14];
    const float* bhh3 = (const float*)d_in[15];
    const float* Wfc  = (const float*)d_in[16];
    const float* bfc  = (const float*)d_in[17];

    float* out  = (float*)d_out;
    float* xmid = out;                  // (64,2048,20)
    float* xout = out + 2621440;        // (64,2048,20)
    float* h1f  = out + 5242880;        // (64,384)
    float* h2f  = out + 5267456;        // (64,16)
    float* h3f  = out + 5268480;        // (64,20)

    char* ws = (char*)d_ws;
    unsigned* sxT = (unsigned*)(ws + 1048576);

    hipMemsetAsync(sxT, 0, 25165824, stream);  // tag 0 never matches 1..2048
    pack_weights<<<10, 256, 0, stream>>>(Whh1, Wih1, Wih2, ws);
    gru_main<<<128, 768, 0, stream>>>(x, h1, h2, bih1, bhh1, ws,
                                      Whh2, bih2, bhh2, Wfc, bfc,
                                      sxT, xmid, h1f, h2f);
    gru3_bwd<<<64, 128, 0, stream>>>(xmid, h3, Wih3, Whh3, bih3, bhh3,
                                     xout, h3f);
}

// Round 7
// 7925.522 us; speedup vs baseline: 1.0029x; 1.0029x over previous
//
#include <hip/hip_runtime.h>

typedef _Float16 f16x2 __attribute__((ext_vector_type(2)));

union FP16U { _Float16 h; unsigned short u; };

#if __has_builtin(__builtin_amdgcn_sdot4)
__device__ __forceinline__ int sdot4(int a, int b, int c) {
    return __builtin_amdgcn_sdot4(a, b, c, false);
}
#else
__device__ __forceinline__ int sdot4(int a, int b, int c) {
#pragma unroll
    for (int i = 0; i < 4; ++i)
        c += (int)((char)(a >> (8 * i))) * (int)((char)(b >> (8 * i)));
    return c;
}
#endif

__device__ __forceinline__ float dot2acc(f16x2 a, f16x2 b, float c) {
#if __has_builtin(__builtin_amdgcn_fdot2)
    return __builtin_amdgcn_fdot2(a, b, c, false);
#else
    return c + (float)a[0] * (float)b[0] + (float)a[1] * (float)b[1];
#endif
}

__device__ __forceinline__ float sigmoidf_(float x) {
    return __builtin_amdgcn_rcpf(1.f + __expf(-x));
}

__device__ __forceinline__ float tanhf_(float x) {
    float a = fabsf(x);
    float e = __expf(-2.f * a);
    float r = (1.f - e) * __builtin_amdgcn_rcpf(1.f + e);
    return copysignf(r, x);
}

#define RING 64

// ws layout (bytes):
//   0        wpk   512*8*6 int4 (393216)  per-thread VGPR gate weights
//   393216   wpl   512*6  int4  (49152)   per-thread LDS-private row (z,s=2)
//   442368   xwp   1152*8 int   (36864)   Wih1 int8 rows (5 dwords + pad)
//   479232   ch    1152 f32     (4608)    Whh row coef = max/16129
//   483840   cx    1152 f32     (4608)    Wih1 row coef = max/(127*20)
//   524288   hw    64*64*384 u32 (6291456) tagged fp16 h ring
//   6815744  prog  64 u32                 consumer progress
static const int GG_[8] = {0, 0, 0, 1, 1, 2, 2, 2};
static const int SS_[8] = {0, 1, 2, 0, 1, 0, 1, 2};

__global__ void pack_scales(const float* __restrict__ Whh1,
                            const float* __restrict__ Wih1,
                            char* __restrict__ wsb) {
    int r = blockIdx.x * 256 + threadIdx.x;
    if (r >= 1152) return;
    float* ch = (float*)(wsb + 479232);
    float* cx = (float*)(wsb + 483840);
    int* xwp = (int*)(wsb + 442368);
    float mx = 0.f;
    for (int k = 0; k < 384; ++k) mx = fmaxf(mx, fabsf(Whh1[r * 384 + k]));
    ch[r] = mx / 16129.f;
    float mxx = 0.f;
    for (int k = 0; k < 20; ++k) mxx = fmaxf(mxx, fabsf(Wih1[r * 20 + k]));
    cx[r] = mxx / (127.f * 20.f);
    float invx = (mxx > 0.f) ? 127.f / mxx : 0.f;
    for (int d = 0; d < 5; ++d) {
        int w = 0;
        for (int i = 0; i < 4; ++i) {
            int q = (int)rintf(Wih1[r * 20 + d * 4 + i] * invx);
            w |= (q & 255) << (8 * i);
        }
        xwp[r * 8 + d] = w;
    }
    xwp[r * 8 + 5] = 0; xwp[r * 8 + 6] = 0; xwp[r * 8 + 7] = 0;
}

__global__ void pack_wv(const float* __restrict__ Whh1,
                        char* __restrict__ wsb) {
    int e = blockIdx.x * 256 + threadIdx.x;
    if (e >= 27648) return;
    const float* ch = (const float*)(wsb + 479232);
    int row, k0, outidx;
    if (e < 24576) {
        int tid = e / 48, rem = e % 48, ridx = rem / 6, m = rem % 6;
        int jl = tid >> 2, kq = tid & 3;
        row = GG_[ridx] * 384 + jl + 128 * SS_[ridx];
        k0 = kq * 96 + m * 16;
        outidx = e;
    } else {
        int e2 = e - 24576;
        int tid = e2 / 6, m = e2 % 6;
        int jl = tid >> 2, kq = tid & 3;
        row = 640 + jl;          // g=1 (z), s=2
        k0 = kq * 96 + m * 16;
        outidx = 24576 + e2;
    }
    float mx = ch[row] * 16129.f;
    float inv = (mx > 0.f) ? 127.f / mx : 0.f;
    int4 v;
    int* vp = (int*)&v;
    for (int c = 0; c < 4; ++c) {
        int w = 0;
        for (int i = 0; i < 4; ++i) {
            int q = (int)rintf(Whh1[row * 384 + k0 + c * 4 + i] * inv);
            w |= (q & 255) << (8 * i);
        }
        vp[c] = w;
    }
    ((int4*)wsb)[outidx] = v;
}

__device__ __forceinline__ void qpackx(float4 v, int& w1, int& w2) {
    w1 = 0; w2 = 0;
    float c[4] = {v.x, v.y, v.z, v.w};
#pragma unroll
    for (int i = 0; i < 4; ++i) {
        float s = c[i] * 20.f;
        int q1 = (int)rintf(fminf(fmaxf(s, -127.f), 127.f));
        int q2 = (int)rintf(fminf(fmaxf((s - (float)q1) * 256.f, -127.f), 127.f));
        w1 |= (q1 & 255) << (8 * i);
        w2 |= (q2 & 255) << (8 * i);
    }
}

// ---------------------------------------------------------------------------
// gru_main: blocks 0..63 = GRU1 producers (512 thr, 8 gate-rows in VGPR,
// 1 in LDS, kq-in-lane shfl reduce, ONE barrier/step). Blocks 64..127 =
// consumers: poll tagged h, compute xp2 fp16 + GRU2 + ReLU + FC.
// ---------------------------------------------------------------------------
__global__ __launch_bounds__(512, 2) void gru_main(
    const float* __restrict__ x, const float* __restrict__ h1_0,
    const float* __restrict__ h2_0,
    const float* __restrict__ bih1, const float* __restrict__ bhh1,
    const char* __restrict__ wsb,
    const float* __restrict__ Wih2,
    const float* __restrict__ Whh2, const float* __restrict__ bih2,
    const float* __restrict__ bhh2,
    const float* __restrict__ Wfc, const float* __restrict__ bfc,
    unsigned* __restrict__ hw, unsigned* __restrict__ prog,
    float* __restrict__ xmid,
    float* __restrict__ h1f_o, float* __restrict__ h2f_o) {
    const int bid = blockIdx.x;
    const int tid = threadIdx.x;

    __shared__ __align__(16) int4 wprivL[512 * 6];
    __shared__ int xwL[1152 * 8];
    __shared__ float chL[1152], cxL[1152];
    __shared__ float cbR[384], cbZ[384], cbNX[384], cbNH[384];
    __shared__ __align__(16) char h1q1[2][512];
    __shared__ __align__(16) char h1q2[2][512];
    __shared__ int xsb[2][2][8];
    __shared__ _Float16 hbuf[2][384];
    __shared__ float p2s[48 * 9 + 16];

    if (bid >= 64) {
        // ------------------------- consumer -------------------------
        const int b = bid - 64;
        const int l = tid;
        const int o = (tid < 384) ? tid / 8 : 0;
        const int seg = (tid < 384) ? tid % 8 : 0;
        f16x2 wf[24];
        if (tid < 384) {
#pragma unroll
            for (int k = 0; k < 24; ++k) {
                f16x2 w;
                w[0] = (_Float16)Wih2[o * 384 + seg * 48 + 2 * k];
                w[1] = (_Float16)Wih2[o * 384 + seg * 48 + 2 * k + 1];
                wf[k] = w;
            }
        }
        float w2r[16]; float bx2 = 0.f, bh2 = 0.f;
        if (l < 48) {
#pragma unroll
            for (int k = 0; k < 16; ++k) w2r[k] = Whh2[l * 16 + k];
            bx2 = bih2[l]; bh2 = bhh2[l];
        }
        float wfc[16]; float bf = 0.f;
        if (l < 20) {
#pragma unroll
            for (int k = 0; k < 16; ++k) wfc[k] = Wfc[l * 16 + k];
            bf = bfc[l];
        }
        float h2 = (l < 16) ? h2_0[b * 16 + l] : 0.f;
        float* xm = xmid + (size_t)b * 40960;
        const unsigned* hwb = hw + (size_t)b * RING * 384;

        for (int t = 0; t < 2048; ++t) {
            if (tid < 384) {
                const unsigned want = (unsigned)(t + 1);
                const unsigned* p = &hwb[((t + 1) & (RING - 1)) * 384 + tid];
                unsigned w;
                do {
                    w = __hip_atomic_load(p, __ATOMIC_RELAXED,
                                          __HIP_MEMORY_SCOPE_AGENT);
                } while ((w >> 16) != want);
                FP16U u; u.u = (unsigned short)(w & 0xffffu);
                hbuf[t & 1][tid] = u.h;
            }
            if (tid == 0 && (t & 15) == 0)
                __hip_atomic_store(&prog[b], (unsigned)t, __ATOMIC_RELAXED,
                                   __HIP_MEMORY_SCOPE_AGENT);
            __syncthreads();
            if (tid < 384) {
                const f16x2* hp = (const f16x2*)&hbuf[t & 1][seg * 48];
                float a = 0.f;
#pragma unroll
                for (int k = 0; k < 24; ++k) a = dot2acc(wf[k], hp[k], a);
                p2s[o * 9 + seg] = a;
            }
            __syncthreads();
            if (tid < 64) {
                float ax = 0.f;
                if (l < 48) {
                    ax = bx2;
#pragma unroll
                    for (int k = 0; k < 8; ++k) ax += p2s[l * 9 + k];
                }
                float ah = bh2;
#pragma unroll
                for (int k = 0; k < 16; ++k) ah += __shfl(h2, k) * w2r[k];
                float s_   = ax + ah;
                float zpre = __shfl(s_, (16 + l) & 63);
                float xn3  = __shfl(ax, (32 + l) & 63);
                float ghn  = __shfl(ah, (32 + l) & 63);
                float r2 = sigmoidf_(s_);
                float z2 = sigmoidf_(zpre);
                float n2 = tanhf_(xn3 + r2 * ghn);
                float h2n = (1.f - z2) * n2 + z2 * h2;
                if (l < 16) h2 = h2n;
                float y2 = fmaxf(h2n, 0.f);
                float a = bf;
#pragma unroll
                for (int k = 0; k < 16; ++k) a += __shfl(y2, k) * wfc[k];
                if (l < 20) xm[t * 20 + l] = 2.f * tanhf_(a);
            }
        }
        if (l < 16) h2f_o[b * 16 + l] = h2;
        return;
    }

    // ------------------------- producer -------------------------
    const int b = bid;
    const int jl = tid >> 2, kq = tid & 3;

    // VGPR gate weights: 8 rows x 6 quads
    int4 Wv[48];
    {
        const int4* wp = (const int4*)wsb + (size_t)tid * 48;
#pragma unroll
        for (int c = 0; c < 48; ++c) Wv[c] = wp[c];
    }
    // cooperative LDS fills
    {
        const int4* wpl = (const int4*)(wsb + 393216);
        for (int i = tid; i < 3072; i += 512) wprivL[i] = wpl[i];
        const int* xg = (const int*)(wsb + 442368);
        for (int i = tid; i < 9216; i += 512) xwL[i] = xg[i];
        const float* chg = (const float*)(wsb + 479232);
        const float* cxg = (const float*)(wsb + 483840);
        for (int i = tid; i < 1152; i += 512) { chL[i] = chg[i]; cxL[i] = cxg[i]; }
        for (int i = tid; i < 384; i += 512) {
            cbR[i]  = bih1[i] + bhh1[i];
            cbZ[i]  = bih1[384 + i] + bhh1[384 + i];
            cbNX[i] = bih1[768 + i];
            cbNH[i] = bhh1[768 + i];
        }
    }
    float hp0 = 0.f, hp1 = 0.f, hp2 = 0.f;
    if (kq == 0) {
        hp0 = h1_0[b * 384 + jl];
        hp1 = h1_0[b * 384 + jl + 128];
        hp2 = h1_0[b * 384 + jl + 256];
    }
    if (tid < 384) {
        float h = h1_0[b * 384 + tid];
        float hs = fminf(fmaxf(h * 127.f, -127.f), 127.f);
        int q1 = (int)rintf(hs);
        int q2 = min(127, max(-127, (int)rintf((hs - (float)q1) * 256.f)));
        h1q1[0][tid] = (char)q1;
        h1q2[0][tid] = (char)q2;
    }
    const float* xb = x + (size_t)b * 40960;
    if (tid < 16) { xsb[tid / 8][0][tid % 8] = 0; xsb[tid / 8][1][tid % 8] = 0; }
    __syncthreads();
    if (tid < 10) {
        int buf = tid / 5, i = tid % 5;
        float4 v = *(const float4*)(xb + buf * 20 + i * 4);
        int w1, w2; qpackx(v, w1, w2);
        xsb[buf][0][i] = w1; xsb[buf][1][i] = w2;
    }
    unsigned* hwb = hw + (size_t)b * RING * 384;
    __syncthreads();

    // prologue: xproj(0) on kq!=0 lanes
    float xpr = 0.f, xpz = 0.f, xpn = 0.f;
    if (kq != 0) {
        const int j2 = jl + 128 * (kq - 1);
        int s1 = 0, s2 = 0, t1 = 0, t2 = 0, u1 = 0, u2 = 0;
#pragma unroll
        for (int d = 0; d < 6; ++d) {
            int xq1 = xsb[0][0][d], xq2 = xsb[0][1][d];
            int wr = xwL[j2 * 8 + d], wz = xwL[(384 + j2) * 8 + d],
                wn = xwL[(768 + j2) * 8 + d];
            s1 = sdot4(wr, xq1, s1); s2 = sdot4(wr, xq2, s2);
            t1 = sdot4(wz, xq1, t1); t2 = sdot4(wz, xq2, t2);
            u1 = sdot4(wn, xq1, u1); u2 = sdot4(wn, xq2, u2);
        }
        xpr = ((float)s1 + (float)s2 * (1.f / 256)) * cxL[j2];
        xpz = ((float)t1 + (float)t2 * (1.f / 256)) * cxL[384 + j2];
        xpn = ((float)u1 + (float)u2 * (1.f / 256)) * cxL[768 + j2];
    }

    const int lane = tid & 63;
    const int base = lane & ~3;

    for (int t = 0; t < 2048; ++t) {
        if (tid == 511 && (t & 7) == 0 && t >= 48) {
            while ((int)t - (int)__hip_atomic_load(&prog[b], __ATOMIC_RELAXED,
                                                   __HIP_MEMORY_SCOPE_AGENT) >= 40)
                __builtin_amdgcn_s_sleep(8);
        }
        // stage x(t+2)
        if (tid >= 504 && tid < 509 && t + 2 < 2048) {
            int i = tid - 504;
            float4 v = *(const float4*)(xb + (size_t)(t + 2) * 20 + i * 4);
            int w1, w2; qpackx(v, w1, w2);
            xsb[t & 1][0][i] = w1; xsb[t & 1][1][i] = w2;
        }
        // gate dots
        int a0 = 0, a1 = 0, a2 = 0, a3 = 0, a4 = 0, a5 = 0, a6 = 0, a7 = 0, a8 = 0;
        int r0 = 0, r1 = 0, r2 = 0;
        {
            const char* hb1 = &h1q1[t & 1][0];
            const char* hb2 = &h1q2[t & 1][0];
#pragma unroll
            for (int m = 0; m < 6; ++m) {
                int4 h1v = *(const int4*)(hb1 + kq * 96 + m * 16);
                int4 h2v = *(const int4*)(hb2 + kq * 96 + m * 16);
                int4 wlv = wprivL[tid * 6 + m];
#define D4(A, W) A = sdot4((W).x, h1v.x, A); A = sdot4((W).y, h1v.y, A); \
                 A = sdot4((W).z, h1v.z, A); A = sdot4((W).w, h1v.w, A);
#define D4R(A, W) A = sdot4((W).x, h2v.x, A); A = sdot4((W).y, h2v.y, A); \
                  A = sdot4((W).z, h2v.z, A); A = sdot4((W).w, h2v.w, A);
                D4(a0, Wv[m])      D4(a1, Wv[6 + m])  D4(a2, Wv[12 + m])
                D4(a3, Wv[18 + m]) D4(a4, Wv[24 + m]) D4(a5, Wv[30 + m])
                D4(a6, Wv[36 + m]) D4(a7, Wv[42 + m]) D4(a8, wlv)
                D4R(r0, Wv[30 + m]) D4R(r1, Wv[36 + m]) D4R(r2, Wv[42 + m])
#undef D4
#undef D4R
            }
        }
        // reduce over kq (lane bits 0,1)
#define RED(A) A += __shfl_xor(A, 1); A += __shfl_xor(A, 2);
        RED(a0) RED(a1) RED(a2) RED(a3) RED(a4) RED(a5) RED(a6) RED(a7) RED(a8)
        RED(r0) RED(r1) RED(r2)
#undef RED
        // converged shfls: xp from kq=s+1 lanes to kq=0
        float xr_0 = __shfl(xpr, base + 1), xz_0 = __shfl(xpz, base + 1),
              xn_0 = __shfl(xpn, base + 1);
        float xr_1 = __shfl(xpr, base + 2), xz_1 = __shfl(xpz, base + 2),
              xn_1 = __shfl(xpn, base + 2);
        float xr_2 = __shfl(xpr, base + 3), xz_2 = __shfl(xpz, base + 3),
              xn_2 = __shfl(xpn, base + 3);
        float hn0 = 0.f, hn1 = 0.f, hn2 = 0.f;
        if (kq == 0) {
#pragma unroll
            for (int s = 0; s < 3; ++s) {
                const int j = jl + 128 * s;
                float accR = (s == 0) ? (float)a0 : (s == 1) ? (float)a1 : (float)a2;
                float accZ = (s == 0) ? (float)a3 : (s == 1) ? (float)a4 : (float)a8;
                float accN = (s == 0) ? (float)a5 : (s == 1) ? (float)a6 : (float)a7;
                float accN2 = (s == 0) ? (float)r0 : (s == 1) ? (float)r1 : (float)r2;
                float xr = (s == 0) ? xr_0 : (s == 1) ? xr_1 : xr_2;
                float xz = (s == 0) ? xz_0 : (s == 1) ? xz_1 : xz_2;
                float xn = (s == 0) ? xn_0 : (s == 1) ? xn_1 : xn_2;
                float ar = accR * chL[j] + xr + cbR[j];
                float az = accZ * chL[384 + j] + xz + cbZ[j];
                float anh = (accN + accN2 * (1.f / 256)) * chL[768 + j] + cbNH[j];
                float anx = xn + cbNX[j];
                float rg = sigmoidf_(ar), zg = sigmoidf_(az);
                float ng = tanhf_(anx + rg * anh);
                float hprev = (s == 0) ? hp0 : (s == 1) ? hp1 : hp2;
                float hnew = (1.f - zg) * ng + zg * hprev;
                if (s == 0) { hp0 = hnew; hn0 = hnew; }
                else if (s == 1) { hp1 = hnew; hn1 = hnew; }
                else { hp2 = hnew; hn2 = hnew; }
            }
        }
        // broadcast new h to kq!=0 lanes
        float hv0 = __shfl(hn0, base), hv1 = __shfl(hn1, base),
              hv2 = __shfl(hn2, base);
        if (kq != 0) {
            const int j2 = jl + 128 * (kq - 1);
            float h = (kq == 1) ? hv0 : (kq == 2) ? hv1 : hv2;
            float hs = fminf(fmaxf(h * 127.f, -127.f), 127.f);
            int q1 = (int)rintf(hs);
            int q2 = min(127, max(-127, (int)rintf((hs - (float)q1) * 256.f)));
            h1q1[(t + 1) & 1][j2] = (char)q1;
            h1q2[(t + 1) & 1][j2] = (char)q2;
            FP16U u; u.h = (_Float16)h;
            __hip_atomic_store(&hwb[((t + 1) & (RING - 1)) * 384 + j2],
                               ((unsigned)(t + 1) << 16) | (unsigned)u.u,
                               __ATOMIC_RELAXED, __HIP_MEMORY_SCOPE_AGENT);
            // xproj for t+1
            if (t + 1 < 2048) {
                int s1 = 0, s2 = 0, t1 = 0, t2 = 0, u1 = 0, u2 = 0;
#pragma unroll
                for (int d = 0; d < 6; ++d) {
                    int xq1 = xsb[(t + 1) & 1][0][d], xq2 = xsb[(t + 1) & 1][1][d];
                    int wr = xwL[j2 * 8 + d], wz = xwL[(384 + j2) * 8 + d],
                        wn = xwL[(768 + j2) * 8 + d];
                    s1 = sdot4(wr, xq1, s1); s2 = sdot4(wr, xq2, s2);
                    t1 = sdot4(wz, xq1, t1); t2 = sdot4(wz, xq2, t2);
                    u1 = sdot4(wn, xq1, u1); u2 = sdot4(wn, xq2, u2);
                }
                xpr = ((float)s1 + (float)s2 * (1.f / 256)) * cxL[j2];
                xpz = ((float)t1 + (float)t2 * (1.f / 256)) * cxL[384 + j2];
                xpn = ((float)u1 + (float)u2 * (1.f / 256)) * cxL[768 + j2];
            }
        }
        __syncthreads();
    }
    if (kq == 0) {
        h1f_o[b * 384 + jl] = hp0;
        h1f_o[b * 384 + jl + 128] = hp1;
        h1f_o[b * 384 + jl + 256] = hp2;
    }
}

// ---------------------------------------------------------------------------
// GRU3 on flip(x_mid): wave0 x-projection into LDS ring; wave1 recurrent.
// ---------------------------------------------------------------------------
__global__ __launch_bounds__(128) void gru3_bwd(
    const float* __restrict__ xmid, const float* __restrict__ h3_0,
    const float* __restrict__ Wih3, const float* __restrict__ Whh3,
    const float* __restrict__ bih3, const float* __restrict__ bhh3,
    float* __restrict__ xout, float* __restrict__ h3f_o) {
    const int b = blockIdx.x, tid = threadIdx.x;
    __shared__ float ring[128 * 64];
    __shared__ int flags[128];
    __shared__ int consL;
    if (tid < 128) flags[tid] = 0;
    if (tid == 0) consL = 0;
    __syncthreads();
    const float* xm = xmid + (size_t)b * 40960;

    if (tid < 64) {
        const int l = tid;
        float wi3[20]; float bx3 = 0.f;
        if (l < 60) {
#pragma unroll
            for (int k = 0; k < 20; ++k) wi3[k] = Wih3[l * 20 + k];
            bx3 = bih3[l];
        }
        float pr[4];
#pragma unroll
        for (int i = 0; i < 4; ++i)
            pr[i] = (l < 20) ? xm[(2047 - i) * 20 + l] : 0.f;
        int lastcons = 0;
        for (int s = 0; s < 2048; ++s) {
            if (s - lastcons >= 112) {
                do {
                    lastcons = __hip_atomic_load(&consL, __ATOMIC_RELAXED,
                                                 __HIP_MEMORY_SCOPE_WORKGROUP);
                } while (s - lastcons >= 112);
            }
            float xv = pr[s & 3];
            if (l < 20 && s + 4 < 2048) pr[s & 3] = xm[(2043 - s) * 20 + l];
            float ax = bx3;
#pragma unroll
            for (int k = 0; k < 20; ++k) ax += __shfl(xv, k) * wi3[k];
            if (l < 60) ring[(s & 127) * 64 + l] = ax;
            __threadfence_block();
            if (l == 0)
                __hip_atomic_store(&flags[s & 127], s + 1, __ATOMIC_RELEASE,
                                   __HIP_MEMORY_SCOPE_WORKGROUP);
        }
    } else {
        const int l = tid - 64;
        float wh3[20]; float bh3v = 0.f;
        if (l < 60) {
#pragma unroll
            for (int k = 0; k < 20; ++k) wh3[k] = Whh3[l * 20 + k];
            bh3v = bhh3[l];
        }
        float h3 = (l < 20) ? h3_0[b * 20 + l] : 0.f;
        float* xo = xout + (size_t)b * 40960;
        for (int s = 0; s < 2048; ++s) {
            while (__hip_atomic_load(&flags[s & 127], __ATOMIC_ACQUIRE,
                                     __HIP_MEMORY_SCOPE_WORKGROUP) != s + 1) {}
            float ax = (l < 60) ? ring[(s & 127) * 64 + l] : 0.f;
            float ah = bh3v;
#pragma unroll
            for (int k = 0; k < 20; ++k) ah += __shfl(h3, k) * wh3[k];
            float s_   = ax + ah;
            float zpre = __shfl(s_, (20 + l) & 63);
            float xn_  = __shfl(ax, (40 + l) & 63);
            float ghn  = __shfl(ah, (40 + l) & 63);
            float r = sigmoidf_(s_);
            float z = sigmoidf_(zpre);
            float n = tanhf_(xn_ + r * ghn);
            float hn = (1.f - z) * n + z * h3;
            if (l < 20) {
                h3 = hn;
                xo[s * 20 + l] = tanhf_(hn);
            }
            if (l == 0 && (s & 31) == 31)
                __hip_atomic_store(&consL, s + 1, __ATOMIC_RELAXED,
                                   __HIP_MEMORY_SCOPE_WORKGROUP);
        }
        if (l < 20) h3f_o[b * 20 + l] = h3;
    }
}

extern "C" void kernel_launch(void* const* d_in, const int* in_sizes, int n_in,
                              void* d_out, int out_size, void* d_ws, size_t ws_size,
                              hipStream_t stream) {
    const float* x    = (const float*)d_in[0];
    const float* h1   = (const float*)d_in[1];
    const float* h2   = (const float*)d_in[2];
    const float* h3   = (const float*)d_in[3];
    const float* Wih1 = (const float*)d_in[4];
    const float* Whh1 = (const float*)d_in[5];
    const float* bih1 = (const float*)d_in[6];
    const float* bhh1 = (const float*)d_in[7];
    const float* Wih2 = (const float*)d_in[8];
    const float* Whh2 = (const float*)d_in[9];
    const float* bih2 = (const float*)d_in[10];
    const float* bhh2 = (const float*)d_in[11];
    const float* Wih3 = (const float*)d_in[12];
    const float* Whh3 = (const float*)d_in[13];
    const float* bih3 = (const float*)d_in[14];
    const float* bhh3 = (const float*)d_in[15];
    const float* Wfc  = (const float*)d_in[16];
    const float* bfc  = (const float*)d_in[17];

    float* out  = (float*)d_out;
    float* xmid = out;                  // (64,2048,20)
    float* xout = out + 2621440;        // (64,2048,20)
    float* h1f  = out + 5242880;        // (64,384)
    float* h2f  = out + 5267456;        // (64,16)
    float* h3f  = out + 5268480;        // (64,20)

    char* ws = (char*)d_ws;
    unsigned* hw   = (unsigned*)(ws + 524288);
    unsigned* prog = (unsigned*)(ws + 6815744);

    hipMemsetAsync(prog, 0, 256, stream);
    pack_scales<<<5, 256, 0, stream>>>(Whh1, Wih1, ws);
    pack_wv<<<108, 256, 0, stream>>>(Whh1, ws);
    gru_main<<<128, 512, 0, stream>>>(x, h1, h2, bih1, bhh1, ws,
                                      Wih2, Whh2, bih2, bhh2, Wfc, bfc,
                                      hw, prog, xmid, h1f, h2f);
    gru3_bwd<<<64, 128, 0, stream>>>(xmid, h3, Wih3, Whh3, bih3, bhh3,
                                     xout, h3f);
}